// Round 10
// baseline (120.475 us; speedup 1.0000x reference)
//
#include <hip/hip_runtime.h>

typedef __bf16 bf16x8 __attribute__((ext_vector_type(8)));
typedef float f32x4 __attribute__((ext_vector_type(4)));
typedef float f32x2 __attribute__((ext_vector_type(2)));

#define G_N 2000
#define K_N 64
#define DEG_INN 8
#define DEG_EXTN 16
#define B_N 1024
#define D 128
#define NT_N 10000

// fp8 scale for P/Q tables (values ~N(0,0.014^2); x256 puts them mid e4m3 range)
#define PQ_SCALE 256.0f
#define PQ_INV   (1.0f / 256.0f)

__device__ __forceinline__ float bflo(unsigned int u) { return __uint_as_float(u << 16); }
__device__ __forceinline__ float bfhi(unsigned int u) { return __uint_as_float(u & 0xffff0000u); }
__device__ __forceinline__ float bf2f(unsigned short s) { return __uint_as_float(((unsigned int)s) << 16); }
__device__ __forceinline__ unsigned short f2bf(float f) {
  unsigned int u = __float_as_uint(f);
  u += 0x7fffu + ((u >> 16) & 1u);
  return (unsigned short)(u >> 16);
}
__device__ __forceinline__ unsigned int pack2bf(float lo, float hi) {
  return ((unsigned int)f2bf(hi) << 16) | (unsigned int)f2bf(lo);
}

// ---------------- K0: P=impact@W^T, Q=impact@M^T (fp8 e4m3 x256) + transposes
// grid (157,3): y=0 -> P, y=1 -> Q, y=2 (x<64) -> Ut/Vt/W1t bf16 transposes.
// NOTE (R6 post-mortem): fusing y=0/y=1 into one block (2x acc registers) and
// cutting k3/k4 block counts REGRESSED 134.8->159.1 us. These kernels are
// latency/occupancy-bound, not L2-BW-bound; keep high block counts + low VGPR.
constexpr int LD1 = 136;

__global__ __launch_bounds__(256)
void k0_prep(const float* __restrict__ impact,
             const float* __restrict__ Wm, const float* __restrict__ Mm,
             const float* __restrict__ U, const float* __restrict__ V,
             const float* __restrict__ W1,
             unsigned int* __restrict__ P8, unsigned int* __restrict__ Q8,
             unsigned int* __restrict__ Ut, unsigned int* __restrict__ Vt,
             unsigned int* __restrict__ W1t)
{
  __shared__ __align__(16) unsigned short Bs[128 * LD1];
  __shared__ __align__(16) unsigned short As[64 * LD1];

  const int tid = threadIdx.x;

  if (blockIdx.y == 2) {
    if (blockIdx.x >= 64) return;
    const int t = blockIdx.x * 256 + tid;       // [0, 16384)
    if (t < 8192) {                              // Ut/Vt: k = t>>6 in [0,128), jc = t&63
      int k = t >> 6, jc = t & 63;
      Ut[t] = pack2bf(U[(size_t)(2 * jc) * D + k], U[(size_t)(2 * jc + 1) * D + k]);
      Vt[t] = pack2bf(V[(size_t)(2 * jc) * D + k], V[(size_t)(2 * jc + 1) * D + k]);
    }
    {                                            // W1t: k = t>>6 in [0,256), jc = t&63
      int k = t >> 6, jc = t & 63;
      W1t[t] = pack2bf(W1[(size_t)(2 * jc) * 256 + k], W1[(size_t)(2 * jc + 1) * 256 + k]);
    }
    return;
  }

  const int rowbase = blockIdx.x * 64;
  const float* Bsrc = blockIdx.y ? Mm : Wm;
  unsigned int* dst = blockIdx.y ? Q8 : P8;
  const int wave = tid >> 6, lane = tid & 63;

  for (int i = tid; i < 128 * 32; i += 256) {
    int row = i >> 5, c4 = i & 31;
    float4 v = ((const float4*)Bsrc)[row * 32 + c4];
    *(unsigned int*)(Bs + row * LD1 + c4 * 4)     = pack2bf(v.x, v.y);
    *(unsigned int*)(Bs + row * LD1 + c4 * 4 + 2) = pack2bf(v.z, v.w);
  }
  for (int i = tid; i < 64 * 32; i += 256) {
    int r = i >> 5, c4 = i & 31;
    int gr = rowbase + r; if (gr > NT_N - 1) gr = NT_N - 1;
    float4 v = ((const float4*)impact)[(size_t)gr * 32 + c4];
    *(unsigned int*)(As + r * LD1 + c4 * 4)     = pack2bf(v.x, v.y);
    *(unsigned int*)(As + r * LD1 + c4 * 4 + 2) = pack2bf(v.z, v.w);
  }
  __syncthreads();

  f32x4 acc[8];
  #pragma unroll
  for (int n = 0; n < 8; ++n) acc[n] = (f32x4){0.f, 0.f, 0.f, 0.f};
  const int qk   = (lane >> 4) * 8;
  const int arow = wave * 16 + (lane & 15);
  #pragma unroll
  for (int kk = 0; kk < 4; ++kk) {
    bf16x8 af = *(const bf16x8*)(As + arow * LD1 + kk * 32 + qk);
    #pragma unroll
    for (int n = 0; n < 8; ++n) {
      bf16x8 bfr = *(const bf16x8*)(Bs + (n * 16 + (lane & 15)) * LD1 + kk * 32 + qk);
      acc[n] = __builtin_amdgcn_mfma_f32_16x16x32_bf16(af, bfr, acc[n], 0, 0, 0);
    }
  }
  __syncthreads();

  // repack C (col=lane&15, row=(lane>>4)*4+reg) into As as bf16 rows
  const int quad = lane >> 4, c = lane & 15;
  #pragma unroll
  for (int n = 0; n < 8; ++n)
    #pragma unroll
    for (int reg = 0; reg < 4; ++reg)
      As[(wave * 16 + quad * 4 + reg) * LD1 + n * 16 + c] = f2bf(acc[n][reg]);
  __syncthreads();

  // write fp8 e4m3 (x256): row = 32 uints (128 fp8)
  for (int i = tid; i < 64 * 32; i += 256) {
    int r = i >> 5, cc = i & 31;
    int gr = rowbase + r;
    if (gr < NT_N) {
      unsigned int u0 = *(unsigned int*)(As + r * LD1 + cc * 4);
      unsigned int u1 = *(unsigned int*)(As + r * LD1 + cc * 4 + 2);
      int p = 0;
      p = __builtin_amdgcn_cvt_pk_fp8_f32(bflo(u0) * PQ_SCALE, bfhi(u0) * PQ_SCALE, p, false);
      p = __builtin_amdgcn_cvt_pk_fp8_f32(bflo(u1) * PQ_SCALE, bfhi(u1) * PQ_SCALE, p, true);
      dst[(size_t)gr * 32 + cc] = (unsigned int)p;
    }
  }
}

// ---------------- K1: fp8 gather-relu-reduce + softmax -> E (bf16) -----------
// Row = 128 fp8 = 16 lanes x uint2 (8 cols each). Slot-sum via shfl_xor(16,32);
// tail: 2 barriers total (R10: removed rg[16] + pg phases).
__global__ __launch_bounds__(256)
void k1_gather(const int* __restrict__ node_type, const int* __restrict__ nbr_type,
               const uint2* __restrict__ P8, const uint2* __restrict__ Q8,
               unsigned short* __restrict__ E16)
{
  __shared__ int nts[64];
  __shared__ int nbs[512];
  __shared__ float rg[4][132];

  const int g    = blockIdx.x;
  const int tid  = threadIdx.x;
  const int wave = tid >> 6, lane = tid & 63;
  const int slot = lane >> 4, cl = lane & 15;

  if (tid < 64) nts[tid] = node_type[g * K_N + tid];
  nbs[tid]       = nbr_type[(size_t)g * 512 + tid];
  nbs[256 + tid] = nbr_type[(size_t)g * 512 + 256 + tid];
  __syncthreads();

  float acc[8];
  #pragma unroll
  for (int i = 0; i < 8; ++i) acc[i] = 0.f;

  for (int it = 0; it < 4; ++it) {
    const int r = wave * 16 + it * 4 + slot;
    uint2 sv = P8[(size_t)nts[r] * 16 + cl];
    f32x2 a01 = __builtin_amdgcn_cvt_pk_f32_fp8(sv.x, false);
    f32x2 a23 = __builtin_amdgcn_cvt_pk_f32_fp8(sv.x, true);
    f32x2 a45 = __builtin_amdgcn_cvt_pk_f32_fp8(sv.y, false);
    f32x2 a67 = __builtin_amdgcn_cvt_pk_f32_fp8(sv.y, true);
    float rv[8] = {a01[0], a01[1], a23[0], a23[1], a45[0], a45[1], a67[0], a67[1]};
    const int* nb = nbs + r * DEG_INN;
    #pragma unroll
    for (int d = 0; d < DEG_INN; ++d) {
      uint2 qv = Q8[(size_t)nb[d] * 16 + cl];
      f32x2 b01 = __builtin_amdgcn_cvt_pk_f32_fp8(qv.x, false);
      f32x2 b23 = __builtin_amdgcn_cvt_pk_f32_fp8(qv.x, true);
      f32x2 b45 = __builtin_amdgcn_cvt_pk_f32_fp8(qv.y, false);
      f32x2 b67 = __builtin_amdgcn_cvt_pk_f32_fp8(qv.y, true);
      rv[0] += b01[0]; rv[1] += b01[1]; rv[2] += b23[0]; rv[3] += b23[1];
      rv[4] += b45[0]; rv[5] += b45[1]; rv[6] += b67[0]; rv[7] += b67[1];
    }
    #pragma unroll
    for (int i = 0; i < 8; ++i) acc[i] += fmaxf(rv[i], 0.f);
  }

  // sum over the 4 slots in-wave (slots differ in lane bits 4,5)
  #pragma unroll
  for (int i = 0; i < 8; ++i) {
    float v = acc[i];
    v += __shfl_xor(v, 16, 64);
    v += __shfl_xor(v, 32, 64);
    if (lane < 16) rg[wave][lane * 8 + i] = v;   // cl == lane for lane<16
  }
  __syncthreads();

  if (wave == 0) {
    float v0 = (rg[0][lane] + rg[1][lane] + rg[2][lane] + rg[3][lane]) * PQ_INV;
    float v1 = (rg[0][64 + lane] + rg[1][64 + lane] + rg[2][64 + lane] + rg[3][64 + lane]) * PQ_INV;
    float mx = fmaxf(v0, v1);
    #pragma unroll
    for (int o = 32; o; o >>= 1) mx = fmaxf(mx, __shfl_xor(mx, o, 64));
    float e0 = __expf(v0 - mx), e1 = __expf(v1 - mx);
    float s = e0 + e1;
    #pragma unroll
    for (int o = 32; o; o >>= 1) s += __shfl_xor(s, o, 64);
    float inv = 1.f / s;
    E16[(size_t)g * D + lane]      = f2bf(e0 * inv);
    E16[(size_t)g * D + 64 + lane] = f2bf(e1 * inv);
  }
}

// ---------------- K3: ext = E@U^T + Esum@V^T ; X = softmax(relu(ext)) --------
// 1 graph/block (2000 blocks); E in bf16; single-wave butterfly softmax tail.
__global__ __launch_bounds__(256)
void k3_ext(const int* __restrict__ ext_nbr, const unsigned short* __restrict__ E16,
            const unsigned int* __restrict__ Ut, const unsigned int* __restrict__ Vt,
            float* __restrict__ X)
{
  __shared__ float Ev[128], Es[128];
  __shared__ float p0[4][64], p1[4][64];
  __shared__ int en[16];

  const int g   = blockIdx.x;
  const int tid = threadIdx.x;
  const int jc  = tid & 63, grp = tid >> 6;
  const int lane = tid & 63, wave = tid >> 6;

  if (tid < 16) en[tid] = ext_nbr[g * DEG_EXTN + tid];
  __syncthreads();

  if (tid < 128) {
    Ev[tid] = bf2f(E16[(size_t)g * D + tid]);
  } else {
    const int j = tid - 128;
    float a = 0.f;
    #pragma unroll
    for (int d = 0; d < DEG_EXTN; ++d) a += bf2f(E16[(size_t)en[d] * D + j]);
    Es[j] = a;
  }
  __syncthreads();

  const unsigned int* T = (grp & 2) ? Vt : Ut;
  const float* act      = (grp & 2) ? Es : Ev;
  const int k0 = (grp & 1) * 64;
  float s0 = 0.f, s1 = 0.f;
  #pragma unroll 16
  for (int k = 0; k < 64; ++k) {
    unsigned int uu = T[(k0 + k) * 64 + jc];
    float a = act[k0 + k];
    s0 += bflo(uu) * a; s1 += bfhi(uu) * a;
  }
  p0[grp][jc] = s0; p1[grp][jc] = s1;
  __syncthreads();

  // wave 0: cols lane and lane+64; col c -> p{c&1}[grp][c>>1] summed over grp
  if (wave == 0) {
    const int jc2 = lane >> 1;
    const bool hi = lane & 1;
    float va = hi ? (p1[0][jc2] + p1[1][jc2] + p1[2][jc2] + p1[3][jc2])
                  : (p0[0][jc2] + p0[1][jc2] + p0[2][jc2] + p0[3][jc2]);
    float vb = hi ? (p1[0][32 + jc2] + p1[1][32 + jc2] + p1[2][32 + jc2] + p1[3][32 + jc2])
                  : (p0[0][32 + jc2] + p0[1][32 + jc2] + p0[2][32 + jc2] + p0[3][32 + jc2]);
    float r0 = fmaxf(va, 0.f), r1 = fmaxf(vb, 0.f);
    float mx = fmaxf(r0, r1);
    #pragma unroll
    for (int o = 32; o; o >>= 1) mx = fmaxf(mx, __shfl_xor(mx, o, 64));
    float e0 = __expf(r0 - mx), e1 = __expf(r1 - mx);
    float sm = e0 + e1;
    #pragma unroll
    for (int o = 32; o; o >>= 1) sm += __shfl_xor(sm, o, 64);
    float inv = 1.f / sm;
    X[(size_t)g * D + lane]      = e0 * inv;
    X[(size_t)g * D + 64 + lane] = e1 * inv;
  }
}

// ---------------- K4: final MLP + 2-way softmax ------------------------------
// 1 item/block (1024 blocks); single-wave tail (h + W2 dot + softmax in wave 0).
__global__ __launch_bounds__(256)
void k4_mlp(const int* __restrict__ batch, const float* __restrict__ Xv,
            const unsigned int* __restrict__ W1t, const float* __restrict__ b1,
            const float* __restrict__ W2, const float* __restrict__ b2,
            float* __restrict__ out)
{
  __shared__ float feat[256];
  __shared__ float q0[4][64], q1[4][64];

  const int tid = threadIdx.x;
  const int jc = tid & 63, grp = tid >> 6;
  const int lane = tid & 63, wave = tid >> 6;

  const int b = blockIdx.x;
  const int i1 = batch[2 * b], i2 = batch[2 * b + 1];
  if (tid < 128) {
    float e1 = Xv[(size_t)i1 * D + tid], e2 = Xv[(size_t)i2 * D + tid];
    feat[tid]       = e1 * e2;
    feat[128 + tid] = e1 + e2;
  }
  __syncthreads();

  float s0 = 0.f, s1 = 0.f;
  #pragma unroll 16
  for (int k = 0; k < 64; ++k) {
    unsigned int uu = W1t[(grp * 64 + k) * 64 + jc];
    float a = feat[grp * 64 + k];
    s0 += bflo(uu) * a; s1 += bfhi(uu) * a;
  }
  q0[grp][jc] = s0; q1[grp][jc] = s1;
  __syncthreads();

  // wave 0: h for cols lane and lane+64, then both W2 dots via butterfly
  if (wave == 0) {
    const int jc2 = lane >> 1;
    const bool hi = lane & 1;
    float ha = hi ? (q1[0][jc2] + q1[1][jc2] + q1[2][jc2] + q1[3][jc2])
                  : (q0[0][jc2] + q0[1][jc2] + q0[2][jc2] + q0[3][jc2]);
    float hb = hi ? (q1[0][32 + jc2] + q1[1][32 + jc2] + q1[2][32 + jc2] + q1[3][32 + jc2])
                  : (q0[0][32 + jc2] + q0[1][32 + jc2] + q0[2][32 + jc2] + q0[3][32 + jc2]);
    float h0 = fmaxf(ha + b1[lane], 0.f);
    float h1 = fmaxf(hb + b1[64 + lane], 0.f);
    float t0 = W2[lane] * h0 + W2[64 + lane] * h1;
    float t1 = W2[128 + lane] * h0 + W2[192 + lane] * h1;
    #pragma unroll
    for (int o = 32; o; o >>= 1) {
      t0 += __shfl_xor(t0, o, 64);
      t1 += __shfl_xor(t1, o, 64);
    }
    if (lane == 0) {
      float r0 = t0 + b2[0], r1 = t1 + b2[1];
      float m = fmaxf(r0, r1);
      float e0 = __expf(r0 - m), e1 = __expf(r1 - m);
      float inv = 1.f / (e0 + e1);
      out[2 * b]     = e0 * inv;
      out[2 * b + 1] = e1 * inv;
    }
  }
}

// ---------------- launch -----------------------------------------------------
extern "C" void kernel_launch(void* const* d_in, const int* in_sizes, int n_in,
                              void* d_out, int out_size, void* d_ws, size_t ws_size,
                              hipStream_t stream) {
  const int* batch     = (const int*)d_in[0];
  const int* node_type = (const int*)d_in[1];
  const int* nbr_type  = (const int*)d_in[2];
  const int* ext_nbr   = (const int*)d_in[3];
  const float* impact  = (const float*)d_in[4];
  const float* W       = (const float*)d_in[5];
  const float* M       = (const float*)d_in[6];
  const float* U       = (const float*)d_in[7];
  const float* V       = (const float*)d_in[8];
  const float* W1      = (const float*)d_in[9];
  const float* b1      = (const float*)d_in[10];
  const float* W2      = (const float*)d_in[11];
  const float* b2      = (const float*)d_in[12];
  float* out           = (float*)d_out;

  unsigned short* E16 = (unsigned short*)d_ws;              // 2000*128 bf16
  float* X = (float*)(E16 + (size_t)G_N * D);               // 2000*128 f32
  unsigned int* P8  = (unsigned int*)(X + (size_t)G_N * D); // 10000*32 uints (fp8 x4)
  unsigned int* Q8  = P8 + (size_t)NT_N * 32;               // 10000*32
  unsigned int* Ut  = Q8 + (size_t)NT_N * 32;               // 8192
  unsigned int* Vt  = Ut + 8192;                            // 8192
  unsigned int* W1t = Vt + 8192;                            // 16384

  k0_prep<<<dim3((NT_N + 63) / 64, 3), 256, 0, stream>>>(impact, W, M, U, V, W1,
                                                         P8, Q8, Ut, Vt, W1t);
  k1_gather<<<G_N, 256, 0, stream>>>(node_type, nbr_type,
                                     (const uint2*)P8, (const uint2*)Q8, E16);
  k3_ext<<<G_N, 256, 0, stream>>>(ext_nbr, E16, Ut, Vt, X);
  k4_mlp<<<B_N, 256, 0, stream>>>(batch, X, W1t, b1, W2, b2, out);
}

// Round 11
// 117.841 us; speedup vs baseline: 1.0224x; 1.0224x over previous
//
#include <hip/hip_runtime.h>

typedef __bf16 bf16x8 __attribute__((ext_vector_type(8)));
typedef float f32x4 __attribute__((ext_vector_type(4)));
typedef float f32x2 __attribute__((ext_vector_type(2)));

#define G_N 2000
#define K_N 64
#define DEG_INN 8
#define DEG_EXTN 16
#define B_N 1024
#define D 128
#define NT_N 10000

// fp8 scale for P/Q tables (values ~N(0,0.014^2); x256 puts them mid e4m3 range)
#define PQ_SCALE 256.0f
#define PQ_INV   (1.0f / 256.0f)

__device__ __forceinline__ float bflo(unsigned int u) { return __uint_as_float(u << 16); }
__device__ __forceinline__ float bfhi(unsigned int u) { return __uint_as_float(u & 0xffff0000u); }
__device__ __forceinline__ unsigned short f2bf(float f) {
  unsigned int u = __float_as_uint(f);
  u += 0x7fffu + ((u >> 16) & 1u);
  return (unsigned short)(u >> 16);
}
__device__ __forceinline__ unsigned int pack2bf(float lo, float hi) {
  return ((unsigned int)f2bf(hi) << 16) | (unsigned int)f2bf(lo);
}

// ---------------- K0: P=impact@W^T, Q=impact@M^T (fp8 e4m3 x256) + transposes
// grid (157,3): y=0 -> P, y=1 -> Q, y=2 (x<64) -> Ut/Vt/W1t bf16 transposes.
// NOTE (R6 post-mortem): fusing y=0/y=1 into one block (2x acc registers) and
// cutting k3/k4 block counts REGRESSED 134.8->159.1 us. These kernels are
// latency/occupancy-bound, not L2-BW-bound; keep high block counts + low VGPR.
// NOTE (R10 post-mortem): k1 shfl-slot-reduction + bf16 E regressed
// 118.3->120.5 us (serial shfl chain; byte-savings don't pay). This is R9.
constexpr int LD1 = 136;

__global__ __launch_bounds__(256)
void k0_prep(const float* __restrict__ impact,
             const float* __restrict__ Wm, const float* __restrict__ Mm,
             const float* __restrict__ U, const float* __restrict__ V,
             const float* __restrict__ W1,
             unsigned int* __restrict__ P8, unsigned int* __restrict__ Q8,
             unsigned int* __restrict__ Ut, unsigned int* __restrict__ Vt,
             unsigned int* __restrict__ W1t)
{
  __shared__ __align__(16) unsigned short Bs[128 * LD1];
  __shared__ __align__(16) unsigned short As[64 * LD1];

  const int tid = threadIdx.x;

  if (blockIdx.y == 2) {
    if (blockIdx.x >= 64) return;
    const int t = blockIdx.x * 256 + tid;       // [0, 16384)
    if (t < 8192) {                              // Ut/Vt: k = t>>6 in [0,128), jc = t&63
      int k = t >> 6, jc = t & 63;
      Ut[t] = pack2bf(U[(size_t)(2 * jc) * D + k], U[(size_t)(2 * jc + 1) * D + k]);
      Vt[t] = pack2bf(V[(size_t)(2 * jc) * D + k], V[(size_t)(2 * jc + 1) * D + k]);
    }
    {                                            // W1t: k = t>>6 in [0,256), jc = t&63
      int k = t >> 6, jc = t & 63;
      W1t[t] = pack2bf(W1[(size_t)(2 * jc) * 256 + k], W1[(size_t)(2 * jc + 1) * 256 + k]);
    }
    return;
  }

  const int rowbase = blockIdx.x * 64;
  const float* Bsrc = blockIdx.y ? Mm : Wm;
  unsigned int* dst = blockIdx.y ? Q8 : P8;
  const int wave = tid >> 6, lane = tid & 63;

  for (int i = tid; i < 128 * 32; i += 256) {
    int row = i >> 5, c4 = i & 31;
    float4 v = ((const float4*)Bsrc)[row * 32 + c4];
    *(unsigned int*)(Bs + row * LD1 + c4 * 4)     = pack2bf(v.x, v.y);
    *(unsigned int*)(Bs + row * LD1 + c4 * 4 + 2) = pack2bf(v.z, v.w);
  }
  for (int i = tid; i < 64 * 32; i += 256) {
    int r = i >> 5, c4 = i & 31;
    int gr = rowbase + r; if (gr > NT_N - 1) gr = NT_N - 1;
    float4 v = ((const float4*)impact)[(size_t)gr * 32 + c4];
    *(unsigned int*)(As + r * LD1 + c4 * 4)     = pack2bf(v.x, v.y);
    *(unsigned int*)(As + r * LD1 + c4 * 4 + 2) = pack2bf(v.z, v.w);
  }
  __syncthreads();

  f32x4 acc[8];
  #pragma unroll
  for (int n = 0; n < 8; ++n) acc[n] = (f32x4){0.f, 0.f, 0.f, 0.f};
  const int qk   = (lane >> 4) * 8;
  const int arow = wave * 16 + (lane & 15);
  #pragma unroll
  for (int kk = 0; kk < 4; ++kk) {
    bf16x8 af = *(const bf16x8*)(As + arow * LD1 + kk * 32 + qk);
    #pragma unroll
    for (int n = 0; n < 8; ++n) {
      bf16x8 bfr = *(const bf16x8*)(Bs + (n * 16 + (lane & 15)) * LD1 + kk * 32 + qk);
      acc[n] = __builtin_amdgcn_mfma_f32_16x16x32_bf16(af, bfr, acc[n], 0, 0, 0);
    }
  }
  __syncthreads();

  // repack C (col=lane&15, row=(lane>>4)*4+reg) into As as bf16 rows
  const int quad = lane >> 4, c = lane & 15;
  #pragma unroll
  for (int n = 0; n < 8; ++n)
    #pragma unroll
    for (int reg = 0; reg < 4; ++reg)
      As[(wave * 16 + quad * 4 + reg) * LD1 + n * 16 + c] = f2bf(acc[n][reg]);
  __syncthreads();

  // write fp8 e4m3 (x256): row = 32 uints (128 fp8)
  for (int i = tid; i < 64 * 32; i += 256) {
    int r = i >> 5, cc = i & 31;
    int gr = rowbase + r;
    if (gr < NT_N) {
      unsigned int u0 = *(unsigned int*)(As + r * LD1 + cc * 4);
      unsigned int u1 = *(unsigned int*)(As + r * LD1 + cc * 4 + 2);
      int p = 0;
      p = __builtin_amdgcn_cvt_pk_fp8_f32(bflo(u0) * PQ_SCALE, bfhi(u0) * PQ_SCALE, p, false);
      p = __builtin_amdgcn_cvt_pk_fp8_f32(bflo(u1) * PQ_SCALE, bfhi(u1) * PQ_SCALE, p, true);
      dst[(size_t)gr * 32 + cc] = (unsigned int)p;
    }
  }
}

// ---------------- K1: fp8 gather-relu-reduce + softmax -> E ------------------
// Row = 128 fp8 = 16 lanes x uint2 (8 cols each).
__global__ __launch_bounds__(256)
void k1_gather(const int* __restrict__ node_type, const int* __restrict__ nbr_type,
               const uint2* __restrict__ P8, const uint2* __restrict__ Q8,
               float* __restrict__ E)
{
  __shared__ int nts[64];
  __shared__ int nbs[512];
  __shared__ float rg[16][132];
  __shared__ float pg[128];

  const int g    = blockIdx.x;
  const int tid  = threadIdx.x;
  const int wave = tid >> 6, lane = tid & 63;
  const int slot = lane >> 4, cl = lane & 15;

  if (tid < 64) nts[tid] = node_type[g * K_N + tid];
  nbs[tid]       = nbr_type[(size_t)g * 512 + tid];
  nbs[256 + tid] = nbr_type[(size_t)g * 512 + 256 + tid];
  __syncthreads();

  float acc[8];
  #pragma unroll
  for (int i = 0; i < 8; ++i) acc[i] = 0.f;

  for (int it = 0; it < 4; ++it) {
    const int r = wave * 16 + it * 4 + slot;
    uint2 sv = P8[(size_t)nts[r] * 16 + cl];
    f32x2 a01 = __builtin_amdgcn_cvt_pk_f32_fp8(sv.x, false);
    f32x2 a23 = __builtin_amdgcn_cvt_pk_f32_fp8(sv.x, true);
    f32x2 a45 = __builtin_amdgcn_cvt_pk_f32_fp8(sv.y, false);
    f32x2 a67 = __builtin_amdgcn_cvt_pk_f32_fp8(sv.y, true);
    float rv[8] = {a01[0], a01[1], a23[0], a23[1], a45[0], a45[1], a67[0], a67[1]};
    const int* nb = nbs + r * DEG_INN;
    #pragma unroll
    for (int d = 0; d < DEG_INN; ++d) {
      uint2 qv = Q8[(size_t)nb[d] * 16 + cl];
      f32x2 b01 = __builtin_amdgcn_cvt_pk_f32_fp8(qv.x, false);
      f32x2 b23 = __builtin_amdgcn_cvt_pk_f32_fp8(qv.x, true);
      f32x2 b45 = __builtin_amdgcn_cvt_pk_f32_fp8(qv.y, false);
      f32x2 b67 = __builtin_amdgcn_cvt_pk_f32_fp8(qv.y, true);
      rv[0] += b01[0]; rv[1] += b01[1]; rv[2] += b23[0]; rv[3] += b23[1];
      rv[4] += b45[0]; rv[5] += b45[1]; rv[6] += b67[0]; rv[7] += b67[1];
    }
    #pragma unroll
    for (int i = 0; i < 8; ++i) acc[i] += fmaxf(rv[i], 0.f);
  }

  const int grp = wave * 4 + slot;
  #pragma unroll
  for (int i = 0; i < 8; ++i) rg[grp][cl * 8 + i] = acc[i];
  __syncthreads();

  if (tid < 128) {
    float s = 0.f;
    #pragma unroll
    for (int q = 0; q < 16; ++q) s += rg[q][tid];
    pg[tid] = s;
  }
  __syncthreads();

  if (wave == 0) {
    float v0 = pg[lane] * PQ_INV, v1 = pg[64 + lane] * PQ_INV;  // undo fp8 scale
    float mx = fmaxf(v0, v1);
    #pragma unroll
    for (int o = 32; o; o >>= 1) mx = fmaxf(mx, __shfl_xor(mx, o, 64));
    float e0 = __expf(v0 - mx), e1 = __expf(v1 - mx);
    float s = e0 + e1;
    #pragma unroll
    for (int o = 32; o; o >>= 1) s += __shfl_xor(s, o, 64);
    float inv = 1.f / s;
    E[(size_t)g * D + lane]      = e0 * inv;
    E[(size_t)g * D + 64 + lane] = e1 * inv;
  }
}

// ---------------- K3: ext = E@U^T + Esum@V^T ; X = softmax(relu(ext)) --------
// 1 graph/block (2000 blocks); single-wave butterfly softmax tail (no scr LDS).
__global__ __launch_bounds__(256)
void k3_ext(const int* __restrict__ ext_nbr, const float* __restrict__ E,
            const unsigned int* __restrict__ Ut, const unsigned int* __restrict__ Vt,
            float* __restrict__ X)
{
  __shared__ float Ev[128], Es[128];
  __shared__ float p0[4][64], p1[4][64];
  __shared__ int en[16];

  const int g   = blockIdx.x;
  const int tid = threadIdx.x;
  const int jc  = tid & 63, grp = tid >> 6;
  const int lane = tid & 63, wave = tid >> 6;

  if (tid < 16) en[tid] = ext_nbr[g * DEG_EXTN + tid];
  __syncthreads();

  if (tid < 128) {
    Ev[tid] = E[(size_t)g * D + tid];
  } else {
    const int j = tid - 128;
    float a = 0.f;
    #pragma unroll
    for (int d = 0; d < DEG_EXTN; ++d) a += E[(size_t)en[d] * D + j];
    Es[j] = a;
  }
  __syncthreads();

  const unsigned int* T = (grp & 2) ? Vt : Ut;
  const float* act      = (grp & 2) ? Es : Ev;
  const int k0 = (grp & 1) * 64;
  float s0 = 0.f, s1 = 0.f;
  #pragma unroll 16
  for (int k = 0; k < 64; ++k) {
    unsigned int uu = T[(k0 + k) * 64 + jc];
    float a = act[k0 + k];
    s0 += bflo(uu) * a; s1 += bfhi(uu) * a;
  }
  p0[grp][jc] = s0; p1[grp][jc] = s1;
  __syncthreads();

  // wave 0: cols lane and lane+64; col c -> p{c&1}[grp][c>>1] summed over grp
  if (wave == 0) {
    const int jc2 = lane >> 1;
    const bool hi = lane & 1;
    float va = hi ? (p1[0][jc2] + p1[1][jc2] + p1[2][jc2] + p1[3][jc2])
                  : (p0[0][jc2] + p0[1][jc2] + p0[2][jc2] + p0[3][jc2]);
    float vb = hi ? (p1[0][32 + jc2] + p1[1][32 + jc2] + p1[2][32 + jc2] + p1[3][32 + jc2])
                  : (p0[0][32 + jc2] + p0[1][32 + jc2] + p0[2][32 + jc2] + p0[3][32 + jc2]);
    float r0 = fmaxf(va, 0.f), r1 = fmaxf(vb, 0.f);
    float mx = fmaxf(r0, r1);
    #pragma unroll
    for (int o = 32; o; o >>= 1) mx = fmaxf(mx, __shfl_xor(mx, o, 64));
    float e0 = __expf(r0 - mx), e1 = __expf(r1 - mx);
    float sm = e0 + e1;
    #pragma unroll
    for (int o = 32; o; o >>= 1) sm += __shfl_xor(sm, o, 64);
    float inv = 1.f / sm;
    X[(size_t)g * D + lane]      = e0 * inv;
    X[(size_t)g * D + 64 + lane] = e1 * inv;
  }
}

// ---------------- K4: final MLP + 2-way softmax ------------------------------
// 1 item/block (1024 blocks); single-wave tail (h + W2 dot + softmax in wave 0).
__global__ __launch_bounds__(256)
void k4_mlp(const int* __restrict__ batch, const float* __restrict__ Xv,
            const unsigned int* __restrict__ W1t, const float* __restrict__ b1,
            const float* __restrict__ W2, const float* __restrict__ b2,
            float* __restrict__ out)
{
  __shared__ float feat[256];
  __shared__ float q0[4][64], q1[4][64];

  const int tid = threadIdx.x;
  const int jc = tid & 63, grp = tid >> 6;
  const int lane = tid & 63, wave = tid >> 6;

  const int b = blockIdx.x;
  const int i1 = batch[2 * b], i2 = batch[2 * b + 1];
  if (tid < 128) {
    float e1 = Xv[(size_t)i1 * D + tid], e2 = Xv[(size_t)i2 * D + tid];
    feat[tid]       = e1 * e2;
    feat[128 + tid] = e1 + e2;
  }
  __syncthreads();

  float s0 = 0.f, s1 = 0.f;
  #pragma unroll 16
  for (int k = 0; k < 64; ++k) {
    unsigned int uu = W1t[(grp * 64 + k) * 64 + jc];
    float a = feat[grp * 64 + k];
    s0 += bflo(uu) * a; s1 += bfhi(uu) * a;
  }
  q0[grp][jc] = s0; q1[grp][jc] = s1;
  __syncthreads();

  // wave 0: h for cols lane and lane+64, then both W2 dots via butterfly
  if (wave == 0) {
    const int jc2 = lane >> 1;
    const bool hi = lane & 1;
    float ha = hi ? (q1[0][jc2] + q1[1][jc2] + q1[2][jc2] + q1[3][jc2])
                  : (q0[0][jc2] + q0[1][jc2] + q0[2][jc2] + q0[3][jc2]);
    float hb = hi ? (q1[0][32 + jc2] + q1[1][32 + jc2] + q1[2][32 + jc2] + q1[3][32 + jc2])
                  : (q0[0][32 + jc2] + q0[1][32 + jc2] + q0[2][32 + jc2] + q0[3][32 + jc2]);
    float h0 = fmaxf(ha + b1[lane], 0.f);
    float h1 = fmaxf(hb + b1[64 + lane], 0.f);
    float t0 = W2[lane] * h0 + W2[64 + lane] * h1;
    float t1 = W2[128 + lane] * h0 + W2[192 + lane] * h1;
    #pragma unroll
    for (int o = 32; o; o >>= 1) {
      t0 += __shfl_xor(t0, o, 64);
      t1 += __shfl_xor(t1, o, 64);
    }
    if (lane == 0) {
      float r0 = t0 + b2[0], r1 = t1 + b2[1];
      float m = fmaxf(r0, r1);
      float e0 = __expf(r0 - m), e1 = __expf(r1 - m);
      float inv = 1.f / (e0 + e1);
      out[2 * b]     = e0 * inv;
      out[2 * b + 1] = e1 * inv;
    }
  }
}

// ---------------- launch -----------------------------------------------------
extern "C" void kernel_launch(void* const* d_in, const int* in_sizes, int n_in,
                              void* d_out, int out_size, void* d_ws, size_t ws_size,
                              hipStream_t stream) {
  const int* batch     = (const int*)d_in[0];
  const int* node_type = (const int*)d_in[1];
  const int* nbr_type  = (const int*)d_in[2];
  const int* ext_nbr   = (const int*)d_in[3];
  const float* impact  = (const float*)d_in[4];
  const float* W       = (const float*)d_in[5];
  const float* M       = (const float*)d_in[6];
  const float* U       = (const float*)d_in[7];
  const float* V       = (const float*)d_in[8];
  const float* W1      = (const float*)d_in[9];
  const float* b1      = (const float*)d_in[10];
  const float* W2      = (const float*)d_in[11];
  const float* b2      = (const float*)d_in[12];
  float* out           = (float*)d_out;

  float* E = (float*)d_ws;                                  // 2000*128 f32
  float* X = E + (size_t)G_N * D;                           // 2000*128 f32
  unsigned int* P8  = (unsigned int*)(X + (size_t)G_N * D); // 10000*32 uints (fp8 x4)
  unsigned int* Q8  = P8 + (size_t)NT_N * 32;               // 10000*32
  unsigned int* Ut  = Q8 + (size_t)NT_N * 32;               // 8192
  unsigned int* Vt  = Ut + 8192;                            // 8192
  unsigned int* W1t = Vt + 8192;                            // 16384

  k0_prep<<<dim3((NT_N + 63) / 64, 3), 256, 0, stream>>>(impact, W, M, U, V, W1,
                                                         P8, Q8, Ut, Vt, W1t);
  k1_gather<<<G_N, 256, 0, stream>>>(node_type, nbr_type,
                                     (const uint2*)P8, (const uint2*)Q8, E);
  k3_ext<<<G_N, 256, 0, stream>>>(ext_nbr, E, Ut, Vt, X);
  k4_mlp<<<B_N, 256, 0, stream>>>(batch, X, W1t, b1, W2, b2, out);
}